// Round 8
// baseline (554.506 us; speedup 1.0000x reference)
//
#include <hip/hip_runtime.h>
#include <stdint.h>
#include <math.h>

// Problem constants
#define NPTS 32768
#define PP   5
#define MM   1024
#define JJ   24
#define HH   256

// out (f32 element offsets), total 2,293,760 floats
#define O0 0                // tpose        [1,N,P,3]
#define O1 491520           // tpose_dirs   [1,N,P,3]
#define O2 983040           // resd         [1,N,P,3]
#define O3 1474560          // pflag        [1,N,P]
#define O4 1638400          // init_bigpose [1,N*P,3]
#define O5 2129920          // pnorm        [1,N*P]

typedef unsigned short ushort_t;
typedef unsigned int   uint_t;

// ---------------- LBS transform for one (n,p) row ----------------
__device__ __forceinline__ void transform_one(
    int n, int p, int nn, float pn, float fl,
    float px, float py, float pz, float dx, float dy, float dz,
    const float* __restrict__ pbw,
    const float4* __restrict__ sA4, const float4* __restrict__ sB4,
    float* __restrict__ out)
{
  // gather 24 f32 blend weights (row = 96 B, 16B aligned)
  const float4* bwr = (const float4*)(pbw + ((size_t)p * MM + nn) * JJ);
  float bw[24];
  #pragma unroll
  for (int q = 0; q < 6; ++q) {
    float4 u = bwr[q];
    bw[q*4+0] = u.x; bw[q*4+1] = u.y; bw[q*4+2] = u.z; bw[q*4+3] = u.w;
  }

  float M1[12], M2[12];
  #pragma unroll
  for (int q = 0; q < 12; ++q) { M1[q] = 0.f; M2[q] = 0.f; }
  #pragma unroll
  for (int j = 0; j < 24; ++j) {
    float w = bw[j];
    float4 a0 = sA4[j*3+0], a1 = sA4[j*3+1], a2 = sA4[j*3+2];
    M1[0]=fmaf(w,a0.x,M1[0]); M1[1]=fmaf(w,a0.y,M1[1]); M1[2]=fmaf(w,a0.z,M1[2]); M1[3]=fmaf(w,a0.w,M1[3]);
    M1[4]=fmaf(w,a1.x,M1[4]); M1[5]=fmaf(w,a1.y,M1[5]); M1[6]=fmaf(w,a1.z,M1[6]); M1[7]=fmaf(w,a1.w,M1[7]);
    M1[8]=fmaf(w,a2.x,M1[8]); M1[9]=fmaf(w,a2.y,M1[9]); M1[10]=fmaf(w,a2.z,M1[10]); M1[11]=fmaf(w,a2.w,M1[11]);
    float4 c0 = sB4[j*3+0], c1 = sB4[j*3+1], c2 = sB4[j*3+2];
    M2[0]=fmaf(w,c0.x,M2[0]); M2[1]=fmaf(w,c0.y,M2[1]); M2[2]=fmaf(w,c0.z,M2[2]); M2[3]=fmaf(w,c0.w,M2[3]);
    M2[4]=fmaf(w,c1.x,M2[4]); M2[5]=fmaf(w,c1.y,M2[5]); M2[6]=fmaf(w,c1.z,M2[6]); M2[7]=fmaf(w,c1.w,M2[7]);
    M2[8]=fmaf(w,c2.x,M2[8]); M2[9]=fmaf(w,c2.y,M2[9]); M2[10]=fmaf(w,c2.z,M2[10]); M2[11]=fmaf(w,c2.w,M2[11]);
  }
  // 3x3 inverse via adjugate (A_bw well-conditioned: sigma_min >= cos 0.5)
  float a=M1[0], b=M1[1], c=M1[2];
  float d=M1[4], e=M1[5], f=M1[6];
  float g=M1[8], h=M1[9], i=M1[10];
  float C00 = e*i - f*h, C01 = c*h - b*i, C02 = b*f - c*e;
  float C10 = f*g - d*i, C11 = a*i - c*g, C12 = c*d - a*f;
  float C20 = d*h - e*g, C21 = b*g - a*h, C22 = a*e - b*d;
  float det = a*C00 + b*C10 + c*C20;
  float rd = 1.0f / det;
  float tx = px - M1[3], ty = py - M1[7], tz = pz - M1[11];
  float t0 = rd * (C00*tx + C01*ty + C02*tz);
  float t1 = rd * (C10*tx + C11*ty + C12*tz);
  float t2 = rd * (C20*tx + C21*ty + C22*tz);
  float i0 = M2[0]*t0 + M2[1]*t1 + M2[2]*t2  + M2[3];
  float i1 = M2[4]*t0 + M2[5]*t1 + M2[6]*t2  + M2[7];
  float i2 = M2[8]*t0 + M2[9]*t1 + M2[10]*t2 + M2[11];
  float d0 = rd * (C00*dx + C01*dy + C02*dz);
  float d1 = rd * (C10*dx + C11*dy + C12*dz);
  float d2 = rd * (C20*dx + C21*dy + C22*dz);
  float e0 = M2[0]*d0 + M2[1]*d1 + M2[2]*d2;
  float e1 = M2[4]*d0 + M2[5]*d1 + M2[6]*d2;
  float e2 = M2[8]*d0 + M2[9]*d1 + M2[10]*d2;

  size_t k = (size_t)n * PP + p;   // n-major (matches reference reshape)
  out[O1 + k*3+0] = e0; out[O1 + k*3+1] = e1; out[O1 + k*3+2] = e2;
  out[O3 + k] = fl;
  out[O4 + k*3+0] = i0; out[O4 + k*3+1] = i1; out[O4 + k*3+2] = i2;
  out[O5 + k] = pn;
}

// grid: 640 blocks x 128 threads. block b: p = b>>7, 256 n's, 2 per thread.
__global__ __launch_bounds__(128) void nn_kernel(
    const float* __restrict__ pp0, const float* __restrict__ pp1,
    const float* __restrict__ part_pts, const float* __restrict__ pbw,
    const float* __restrict__ Ag, const float* __restrict__ Bg,
    const int* __restrict__ lengths2, float* __restrict__ out)
{
  __shared__ float4 sPart[MM];   // {x, y, z, |y|^2}
  __shared__ float4 sA4[72];     // A rows 0..2 per joint
  __shared__ float4 sB4[72];     // big_A rows 0..2 per joint
  int t = threadIdx.x;
  int p = blockIdx.x >> 7;
  int n0 = (blockIdx.x & 127) << 8;

  // device-side pose-pair disambiguation (wave-uniform); pose_dirs rows unit-norm
  float s0r0 = pp0[0], s0r1 = pp0[1], s0r2 = pp0[2];
  float nrm = s0r0*s0r0 + s0r1*s0r1 + s0r2*s0r2;
  bool c0_is_dirs = fabsf(nrm - 1.0f) < 1e-4f;
  const float* pose_pts  = c0_is_dirs ? pp1 : pp0;
  const float* pose_dirs = c0_is_dirs ? pp0 : pp1;

  {
    #pragma clang fp contract(off)
    for (int i = t; i < MM; i += 128) {
      float x = part_pts[((size_t)p*MM+i)*3+0];
      float y = part_pts[((size_t)p*MM+i)*3+1];
      float z = part_pts[((size_t)p*MM+i)*3+2];
      float yy = ((x*x) + (y*y)) + (z*z);   // np sum over 3: sequential, no FMA
      sPart[i] = make_float4(x, y, z, yy);
    }
  }
  for (int i = t; i < 72; i += 128) {
    int l = i*4;                 // l%12 in {0,4,8}: never crosses a 12-elem joint row
    int j = l / 12, rc = l % 12;
    float4 qa, qb;
    qa.x = Ag[j*16+rc+0]; qa.y = Ag[j*16+rc+1]; qa.z = Ag[j*16+rc+2]; qa.w = Ag[j*16+rc+3];
    qb.x = Bg[j*16+rc+0]; qb.y = Bg[j*16+rc+1]; qb.z = Bg[j*16+rc+2]; qb.w = Bg[j*16+rc+3];
    sA4[i] = qa; sB4[i] = qb;
  }
  int mlen = lengths2[p]; if (mlen > MM) mlen = MM;
  __syncthreads();

  int n_a = n0 + t, n_b = n0 + 128 + t;
  float xa = pose_pts[n_a*3+0], ya = pose_pts[n_a*3+1], za = pose_pts[n_a*3+2];
  float xb = pose_pts[n_b*3+0], yb = pose_pts[n_b*3+1], zb = pose_pts[n_b*3+2];
  float dxa = pose_dirs[n_a*3+0], dya = pose_dirs[n_a*3+1], dza = pose_dirs[n_a*3+2];
  float dxb = pose_dirs[n_b*3+0], dyb = pose_dirs[n_b*3+1], dzb = pose_dirs[n_b*3+2];

  float bestA = 1e30f, bestB = 1e30f;
  int bmA = 0, bmB = 0;
  {
    #pragma clang fp contract(off)
    float x2a = ((xa*xa) + (ya*ya)) + (za*za);
    float x2b = ((xb*xb) + (yb*yb)) + (zb*zb);
    for (int m = 0; m < mlen; ++m) {
      float4 q = sPart[m];
      float dotA = ((xa*q.x) + (ya*q.y)) + (za*q.z);
      float dA = fmaxf((x2a - (2.0f*dotA)) + q.w, 0.0f);
      if (dA < bestA) { bestA = dA; bmA = m; }   // strict <: first-min like np.argmin
      float dotB = ((xb*q.x) + (yb*q.y)) + (zb*q.z);
      float dB = fmaxf((x2b - (2.0f*dotB)) + q.w, 0.0f);
      if (dB < bestB) { bestB = dB; bmB = m; }
    }
  }
  float pnA = sqrtf(bestA);
  float pnB = sqrtf(bestB);
  float flA = ((double)pnA < 0.08) ? 1.0f : 0.0f;
  float flB = ((double)pnB < 0.08) ? 1.0f : 0.0f;
  transform_one(n_a, p, bmA, pnA, flA, xa, ya, za, dxa, dya, dza, pbw, sA4, sB4, out);
  transform_one(n_b, p, bmB, pnB, flB, xb, yb, zb, dxb, dyb, dzb, pbw, sA4, sB4, out);
}

// ---------------- MLP 3->256->256->3 + residual ----------------
// grid: 5120 blocks x 256 threads; 32 rows per block. ibp/flag relayed via out (f32).
__global__ __launch_bounds__(256) void mlp_kernel(
    const float* __restrict__ W1g, const float* __restrict__ b1g,
    const float* __restrict__ W2g, const float* __restrict__ b2g,
    const float* __restrict__ W3g, const float* __restrict__ b3g,
    float* __restrict__ out)
{
  __shared__ float sH1[256*36];   // h1 as [k][r] (pad 36); reused as h2^T [c][r]
  __shared__ float sW2[32*256];   // one 32-row W2 chunk [k][c]
  __shared__ float sW3[768];      // W3^T [3][256]
  __shared__ float sIBP[96];
  __shared__ float sFlag[32];
  __shared__ float sRed[8*96];

  int t = threadIdx.x;
  size_t row0 = (size_t)blockIdx.x * 32;

  if (t < 96) sIBP[t] = out[O4 + row0*3 + t];
  if (t < 32) sFlag[t] = out[O3 + row0 + t];
  for (int i = t; i < 768; i += 256) {
    int c3 = i >> 8, k = i & 255;
    sW3[i] = W3g[k*3 + c3];
  }
  float w10 = W1g[t], w11 = W1g[256 + t], w12 = W1g[512 + t];
  float bb1 = b1g[t];
  __syncthreads();

  // layer 1: thread t = hidden unit, 32 rows
  {
    float* dst = &sH1[t*36];
    #pragma unroll
    for (int r = 0; r < 32; r += 4) {
      float4 v;
      v.x = fmaxf(fmaf(sIBP[(r+0)*3+2], w12, fmaf(sIBP[(r+0)*3+1], w11, fmaf(sIBP[(r+0)*3+0], w10, bb1))), 0.f);
      v.y = fmaxf(fmaf(sIBP[(r+1)*3+2], w12, fmaf(sIBP[(r+1)*3+1], w11, fmaf(sIBP[(r+1)*3+0], w10, bb1))), 0.f);
      v.z = fmaxf(fmaf(sIBP[(r+2)*3+2], w12, fmaf(sIBP[(r+2)*3+1], w11, fmaf(sIBP[(r+2)*3+0], w10, bb1))), 0.f);
      v.w = fmaxf(fmaf(sIBP[(r+3)*3+2], w12, fmaf(sIBP[(r+3)*3+1], w11, fmaf(sIBP[(r+3)*3+0], w10, bb1))), 0.f);
      *(float4*)&dst[r] = v;
    }
  }

  // layer 2: 4x8 register micro-tile, single-buffered W2 chunks
  int ci = t & 31, ri = t >> 5;
  float acc[4][8];
  #pragma unroll
  for (int ii = 0; ii < 4; ++ii)
    #pragma unroll
    for (int jj = 0; jj < 8; ++jj) acc[ii][jj] = 0.f;

  for (int kc = 0; kc < 8; ++kc) {
    __syncthreads();
    #pragma unroll
    for (int i = 0; i < 8; ++i) {
      *(float4*)&sW2[i*1024 + t*4] = *(const float4*)&W2g[kc*8192 + i*1024 + t*4];
    }
    __syncthreads();
    #pragma unroll 4
    for (int k = 0; k < 32; ++k) {
      const float* Hk = &sH1[(kc*32 + k)*36];
      float4 a = *(const float4*)&Hk[ri*4];
      const float* Wk = &sW2[k*256];
      float4 b0 = *(const float4*)&Wk[ci*4];
      float4 b1 = *(const float4*)&Wk[128 + ci*4];
      float av[4] = {a.x, a.y, a.z, a.w};
      float bv[8] = {b0.x,b0.y,b0.z,b0.w,b1.x,b1.y,b1.z,b1.w};
      #pragma unroll
      for (int ii = 0; ii < 4; ++ii)
        #pragma unroll
        for (int jj = 0; jj < 8; ++jj)
          acc[ii][jj] = fmaf(av[ii], bv[jj], acc[ii][jj]);
    }
  }
  __syncthreads();

  // +b2, relu, write h2^T into sH1 as [c][r]
  #pragma unroll
  for (int jj = 0; jj < 8; ++jj) {
    int c = (jj < 4) ? (ci*4 + jj) : (128 + ci*4 + jj - 4);
    float bb = b2g[c];
    float4 v;
    v.x = fmaxf(acc[0][jj] + bb, 0.f);
    v.y = fmaxf(acc[1][jj] + bb, 0.f);
    v.z = fmaxf(acc[2][jj] + bb, 0.f);
    v.w = fmaxf(acc[3][jj] + bb, 0.f);
    *(float4*)&sH1[c*36 + ri*4] = v;
  }
  __syncthreads();

  // layer 3: 8 column-groups of 32
  {
    int r = t & 31, cg = t >> 5;
    float s0 = 0.f, s1 = 0.f, s2 = 0.f;
    #pragma unroll 4
    for (int cc = 0; cc < 32; ++cc) {
      int c = (cg << 5) + cc;
      float v = sH1[c*36 + r];
      s0 = fmaf(v, sW3[c],       s0);
      s1 = fmaf(v, sW3[256 + c], s1);
      s2 = fmaf(v, sW3[512 + c], s2);
    }
    sRed[cg*96 + r*3+0] = s0;
    sRed[cg*96 + r*3+1] = s1;
    sRed[cg*96 + r*3+2] = s2;
  }
  __syncthreads();

  if (t < 32) {
    float v0 = b3g[0], v1 = b3g[1], v2 = b3g[2];
    #pragma unroll
    for (int g = 0; g < 8; ++g) {
      v0 += sRed[g*96 + t*3+0];
      v1 += sRed[g*96 + t*3+1];
      v2 += sRed[g*96 + t*3+2];
    }
    float fl = sFlag[t];
    float r0 = 0.05f * tanhf(v0) * fl;
    float r1 = 0.05f * tanhf(v1) * fl;
    float r2 = 0.05f * tanhf(v2) * fl;
    float i0 = sIBP[t*3+0], i1 = sIBP[t*3+1], i2 = sIBP[t*3+2];
    size_t k = row0 + t;
    out[O0 + k*3+0] = i0 + r0;
    out[O0 + k*3+1] = i1 + r1;
    out[O0 + k*3+2] = i2 + r2;
    out[O2 + k*3+0] = r0;
    out[O2 + k*3+1] = r1;
    out[O2 + k*3+2] = r2;
  }
}

extern "C" void kernel_launch(void* const* d_in, const int* in_sizes, int n_in,
                              void* d_out, int out_size, void* d_ws, size_t ws_size,
                              hipStream_t stream) {
  (void)out_size; (void)d_ws; (void)ws_size;
  // size-based slot remap (no-op under documented dict order; protective otherwise)
  const int want[13] = {98304, 98304, 15360, 122880, 384, 384, 768, 256, 65536, 256, 768, 3, 5};
  int idx[13];
  bool used[64] = {false};
  for (int L = 0; L < 13; ++L) {
    idx[L] = -1;
    for (int s = 0; s < n_in && s < 64; ++s) {
      if (!used[s] && in_sizes[s] == want[L]) { idx[L] = s; used[s] = true; break; }
    }
    if (idx[L] < 0) idx[L] = L;
  }
  const float* pp0       = (const float*)d_in[idx[0]];
  const float* pp1       = (const float*)d_in[idx[1]];
  const float* part_pts  = (const float*)d_in[idx[2]];
  const float* part_pbw  = (const float*)d_in[idx[3]];
  const float* A         = (const float*)d_in[idx[4]];
  const float* bigA      = (const float*)d_in[idx[5]];
  const float* W1        = (const float*)d_in[idx[6]];
  const float* b1        = (const float*)d_in[idx[7]];
  const float* W2        = (const float*)d_in[idx[8]];
  const float* b2        = (const float*)d_in[idx[9]];
  const float* W3        = (const float*)d_in[idx[10]];
  const float* b3        = (const float*)d_in[idx[11]];
  const int*   lengths2  = (const int*)d_in[idx[12]];
  float* out = (float*)d_out;

  nn_kernel<<<640, 128, 0, stream>>>(pp0, pp1, part_pts, part_pbw,
                                     A, bigA, lengths2, out);
  mlp_kernel<<<5120, 256, 0, stream>>>(W1, b1, W2, b2, W3, b3, out);
}

// Round 9
// 455.770 us; speedup vs baseline: 1.2166x; 1.2166x over previous
//
#include <hip/hip_runtime.h>
#include <stdint.h>
#include <math.h>

// Problem constants
#define NPTS 32768
#define PP   5
#define MM   1024
#define JJ   24
#define HH   256

// out (f32 element offsets), total 2,293,760 floats
#define O0 0                // tpose        [1,N,P,3]
#define O1 491520           // tpose_dirs   [1,N,P,3]
#define O2 983040           // resd         [1,N,P,3]
#define O3 1474560          // pflag        [1,N,P]
#define O4 1638400          // init_bigpose [1,N*P,3]
#define O5 2129920          // pnorm        [1,N*P]

typedef unsigned short ushort_t;
typedef unsigned int   uint_t;
typedef __attribute__((ext_vector_type(8))) short bf16x8;
typedef __attribute__((ext_vector_type(4))) float f32x4;

__device__ __forceinline__ ushort_t f2bf(float f) {
  union { uint_t i; float f; } v; v.f = f;
  uint_t i = v.i;
  return (ushort_t)((i + 0x7FFFu + ((i >> 16) & 1u)) >> 16);  // RNE
}

// ---------------- prep: W2 f32 -> bf16 in MFMA B-fragment order ----------------
// Element (k,n): kc=k>>5, quad=(k&31)>>3, j=k&7, tile=n>>4, lane=quad*16+(n&15)
// idx = kc*8192 + tile*512 + lane*8 + j   (bf16 units; 65536 total = 128 KB)
__global__ __launch_bounds__(256) void prep_w2(const float* __restrict__ W2g,
                                               ushort_t* __restrict__ W2bf)
{
  int k = blockIdx.x;
  int n = threadIdx.x;
  float v = W2g[k*256 + n];
  int kc = k >> 5, quad = (k & 31) >> 3, j = k & 7;
  int tile = n >> 4, lane = quad*16 + (n & 15);
  W2bf[kc*8192 + tile*512 + lane*8 + j] = f2bf(v);
}

// ---------------- LBS transform for one (n,p) row ----------------
__device__ __forceinline__ void transform_one(
    int n, int p, int nn, float pn, float fl,
    float px, float py, float pz, float dx, float dy, float dz,
    const float* __restrict__ pbw,
    const float4* __restrict__ sA4, const float4* __restrict__ sB4,
    float* __restrict__ out)
{
  const float4* bwr = (const float4*)(pbw + ((size_t)p * MM + nn) * JJ);
  float bw[24];
  #pragma unroll
  for (int q = 0; q < 6; ++q) {
    float4 u = bwr[q];
    bw[q*4+0] = u.x; bw[q*4+1] = u.y; bw[q*4+2] = u.z; bw[q*4+3] = u.w;
  }

  float M1[12], M2[12];
  #pragma unroll
  for (int q = 0; q < 12; ++q) { M1[q] = 0.f; M2[q] = 0.f; }
  #pragma unroll
  for (int j = 0; j < 24; ++j) {
    float w = bw[j];
    float4 a0 = sA4[j*3+0], a1 = sA4[j*3+1], a2 = sA4[j*3+2];
    M1[0]=fmaf(w,a0.x,M1[0]); M1[1]=fmaf(w,a0.y,M1[1]); M1[2]=fmaf(w,a0.z,M1[2]); M1[3]=fmaf(w,a0.w,M1[3]);
    M1[4]=fmaf(w,a1.x,M1[4]); M1[5]=fmaf(w,a1.y,M1[5]); M1[6]=fmaf(w,a1.z,M1[6]); M1[7]=fmaf(w,a1.w,M1[7]);
    M1[8]=fmaf(w,a2.x,M1[8]); M1[9]=fmaf(w,a2.y,M1[9]); M1[10]=fmaf(w,a2.z,M1[10]); M1[11]=fmaf(w,a2.w,M1[11]);
    float4 c0 = sB4[j*3+0], c1 = sB4[j*3+1], c2 = sB4[j*3+2];
    M2[0]=fmaf(w,c0.x,M2[0]); M2[1]=fmaf(w,c0.y,M2[1]); M2[2]=fmaf(w,c0.z,M2[2]); M2[3]=fmaf(w,c0.w,M2[3]);
    M2[4]=fmaf(w,c1.x,M2[4]); M2[5]=fmaf(w,c1.y,M2[5]); M2[6]=fmaf(w,c1.z,M2[6]); M2[7]=fmaf(w,c1.w,M2[7]);
    M2[8]=fmaf(w,c2.x,M2[8]); M2[9]=fmaf(w,c2.y,M2[9]); M2[10]=fmaf(w,c2.z,M2[10]); M2[11]=fmaf(w,c2.w,M2[11]);
  }
  float a=M1[0], b=M1[1], c=M1[2];
  float d=M1[4], e=M1[5], f=M1[6];
  float g=M1[8], h=M1[9], i=M1[10];
  float C00 = e*i - f*h, C01 = c*h - b*i, C02 = b*f - c*e;
  float C10 = f*g - d*i, C11 = a*i - c*g, C12 = c*d - a*f;
  float C20 = d*h - e*g, C21 = b*g - a*h, C22 = a*e - b*d;
  float det = a*C00 + b*C10 + c*C20;
  float rd = 1.0f / det;
  float tx = px - M1[3], ty = py - M1[7], tz = pz - M1[11];
  float t0 = rd * (C00*tx + C01*ty + C02*tz);
  float t1 = rd * (C10*tx + C11*ty + C12*tz);
  float t2 = rd * (C20*tx + C21*ty + C22*tz);
  float i0 = M2[0]*t0 + M2[1]*t1 + M2[2]*t2  + M2[3];
  float i1 = M2[4]*t0 + M2[5]*t1 + M2[6]*t2  + M2[7];
  float i2 = M2[8]*t0 + M2[9]*t1 + M2[10]*t2 + M2[11];
  float d0 = rd * (C00*dx + C01*dy + C02*dz);
  float d1 = rd * (C10*dx + C11*dy + C12*dz);
  float d2 = rd * (C20*dx + C21*dy + C22*dz);
  float e0 = M2[0]*d0 + M2[1]*d1 + M2[2]*d2;
  float e1 = M2[4]*d0 + M2[5]*d1 + M2[6]*d2;
  float e2 = M2[8]*d0 + M2[9]*d1 + M2[10]*d2;

  size_t k = (size_t)n * PP + p;   // n-major (matches reference reshape)
  out[O1 + k*3+0] = e0; out[O1 + k*3+1] = e1; out[O1 + k*3+2] = e2;
  out[O3 + k] = fl;
  out[O4 + k*3+0] = i0; out[O4 + k*3+1] = i1; out[O4 + k*3+2] = i2;
  out[O5 + k] = pn;
}

// grid: 640 blocks x 256 threads. block b: p = b>>7, 256 n's, 1 per thread.
// Distance arithmetic bit-identical to the R8-passing version (contract off,
// sequential dot, ((|x|^2 - 2*dot) + |y|^2), max(,0), first-min). 4x unroll
// only batches independent LDS reads; compare chain stays in m-order.
__global__ __launch_bounds__(256) void nn_kernel(
    const float* __restrict__ pp0, const float* __restrict__ pp1,
    const float* __restrict__ part_pts, const float* __restrict__ pbw,
    const float* __restrict__ Ag, const float* __restrict__ Bg,
    const int* __restrict__ lengths2, float* __restrict__ out)
{
  __shared__ float4 sPart[MM];   // {x, y, z, |y|^2}
  __shared__ float4 sA4[72];
  __shared__ float4 sB4[72];
  int t = threadIdx.x;
  int p = blockIdx.x >> 7;
  int n = ((blockIdx.x & 127) << 8) + t;

  // pose-pair disambiguation (wave-uniform); pose_dirs rows unit-norm
  float s0r0 = pp0[0], s0r1 = pp0[1], s0r2 = pp0[2];
  float nrm = s0r0*s0r0 + s0r1*s0r1 + s0r2*s0r2;
  bool c0_is_dirs = fabsf(nrm - 1.0f) < 1e-4f;
  const float* pose_pts  = c0_is_dirs ? pp1 : pp0;
  const float* pose_dirs = c0_is_dirs ? pp0 : pp1;

  {
    #pragma clang fp contract(off)
    for (int i = t; i < MM; i += 256) {
      float x = part_pts[((size_t)p*MM+i)*3+0];
      float y = part_pts[((size_t)p*MM+i)*3+1];
      float z = part_pts[((size_t)p*MM+i)*3+2];
      float yy = ((x*x) + (y*y)) + (z*z);
      sPart[i] = make_float4(x, y, z, yy);
    }
  }
  for (int i = t; i < 72; i += 256) {
    int l = i*4;
    int j = l / 12, rc = l % 12;
    float4 qa, qb;
    qa.x = Ag[j*16+rc+0]; qa.y = Ag[j*16+rc+1]; qa.z = Ag[j*16+rc+2]; qa.w = Ag[j*16+rc+3];
    qb.x = Bg[j*16+rc+0]; qb.y = Bg[j*16+rc+1]; qb.z = Bg[j*16+rc+2]; qb.w = Bg[j*16+rc+3];
    sA4[i] = qa; sB4[i] = qb;
  }
  int mlen = lengths2[p]; if (mlen > MM) mlen = MM;
  __syncthreads();

  float xa = pose_pts[n*3+0], ya = pose_pts[n*3+1], za = pose_pts[n*3+2];
  float dxa = pose_dirs[n*3+0], dya = pose_dirs[n*3+1], dza = pose_dirs[n*3+2];

  float best = 1e30f;
  int bm = 0;
  {
    #pragma clang fp contract(off)
    float x2 = ((xa*xa) + (ya*ya)) + (za*za);
    int m = 0;
    for (; m + 3 < mlen; m += 4) {
      float4 q0 = sPart[m+0];
      float4 q1 = sPart[m+1];
      float4 q2 = sPart[m+2];
      float4 q3 = sPart[m+3];
      float dot0 = ((xa*q0.x) + (ya*q0.y)) + (za*q0.z);
      float dot1 = ((xa*q1.x) + (ya*q1.y)) + (za*q1.z);
      float dot2 = ((xa*q2.x) + (ya*q2.y)) + (za*q2.z);
      float dot3 = ((xa*q3.x) + (ya*q3.y)) + (za*q3.z);
      float d0 = fmaxf((x2 - (2.0f*dot0)) + q0.w, 0.0f);
      float d1 = fmaxf((x2 - (2.0f*dot1)) + q1.w, 0.0f);
      float d2 = fmaxf((x2 - (2.0f*dot2)) + q2.w, 0.0f);
      float d3 = fmaxf((x2 - (2.0f*dot3)) + q3.w, 0.0f);
      if (d0 < best) { best = d0; bm = m+0; }
      if (d1 < best) { best = d1; bm = m+1; }
      if (d2 < best) { best = d2; bm = m+2; }
      if (d3 < best) { best = d3; bm = m+3; }
    }
    for (; m < mlen; ++m) {
      float4 q = sPart[m];
      float dt = ((xa*q.x) + (ya*q.y)) + (za*q.z);
      float dd = fmaxf((x2 - (2.0f*dt)) + q.w, 0.0f);
      if (dd < best) { best = dd; bm = m; }
    }
  }
  float pn = sqrtf(best);
  float fl = ((double)pn < 0.08) ? 1.0f : 0.0f;
  transform_one(n, p, bm, pn, fl, xa, ya, za, dxa, dya, dza, pbw, sA4, sB4, out);
}

// ---------------- MLP via bf16 MFMA ----------------
// grid: 2560 blocks x 256 threads (4 waves); 64 rows/block, 16 rows/wave.
// Layer 1 (f32) computed per-lane directly into A-fragments; layer 2 =
// 16x16x32 bf16 MFMA vs pre-swizzled W2 (global, L2-hot); layer 3 f32 +
// shfl_xor reduce. ibp/flag relayed via out (f32).
__global__ __launch_bounds__(256) void mlp_kernel(
    const float* __restrict__ W1g, const float* __restrict__ b1g,
    const float* __restrict__ b2g, const float* __restrict__ W3g,
    const float* __restrict__ b3g, const ushort_t* __restrict__ W2bf,
    float* __restrict__ out)
{
  __shared__ float sPar[2052];  // [0,768)=W1, [768,1024)=b1, [1024,1280)=b2,
                                // [1280,2048)=W3 (orig [k][3] layout), [2048,2051)=b3
  int t = threadIdx.x;
  int wave = t >> 6, lane = t & 63, quad = lane >> 4, m16 = lane & 15;
  size_t row0 = (size_t)blockIdx.x * 64;

  for (int i = t; i < 2051; i += 256) {
    float v;
    if (i < 768)       v = W1g[i];
    else if (i < 1024) v = b1g[i-768];
    else if (i < 1280) v = b2g[i-1024];
    else if (i < 2048) v = W3g[i-1280];
    else               v = b3g[i-2048];
    sPar[i] = v;
  }
  __syncthreads();

  // A-fragment rows: this lane's h1 row = row0 + wave*16 + m16
  int arow = (int)row0 + wave*16 + m16;
  float x = out[O4 + (size_t)arow*3+0];
  float y = out[O4 + (size_t)arow*3+1];
  float z = out[O4 + (size_t)arow*3+2];

  bf16x8 A[8];
  #pragma unroll
  for (int kc = 0; kc < 8; ++kc) {
    int c0 = kc*32 + quad*8;
    #pragma unroll
    for (int j = 0; j < 8; ++j) {
      int c = c0 + j;
      float h = fmaf(z, sPar[512+c], fmaf(y, sPar[256+c], fmaf(x, sPar[c], sPar[768+c])));
      h = fmaxf(h, 0.f);
      A[kc][j] = (short)f2bf(h);
    }
  }

  f32x4 acc[16];
  #pragma unroll
  for (int nt = 0; nt < 16; ++nt) acc[nt] = (f32x4){0.f, 0.f, 0.f, 0.f};

  #pragma unroll 2
  for (int kc = 0; kc < 8; ++kc) {
    #pragma unroll
    for (int nt = 0; nt < 16; ++nt) {
      bf16x8 B = *(const bf16x8*)(W2bf + kc*8192 + nt*512 + lane*8);
      acc[nt] = __builtin_amdgcn_mfma_f32_16x16x32_bf16(A[kc], B, acc[nt], 0, 0, 0);
    }
  }

  // layer 3: lane holds h2[row=quad*4+reg][col=nt*16+m16]
  #pragma unroll
  for (int reg = 0; reg < 4; ++reg) {
    float p0 = 0.f, p1 = 0.f, p2 = 0.f;
    #pragma unroll
    for (int nt = 0; nt < 16; ++nt) {
      int col = nt*16 + m16;
      float h2 = fmaxf(acc[nt][reg] + sPar[1024+col], 0.f);
      p0 = fmaf(h2, sPar[1280+col*3+0], p0);
      p1 = fmaf(h2, sPar[1280+col*3+1], p1);
      p2 = fmaf(h2, sPar[1280+col*3+2], p2);
    }
    // reduce over the 16 lanes of this quad (xor stays in-group)
    #pragma unroll
    for (int mask = 1; mask < 16; mask <<= 1) {
      p0 += __shfl_xor(p0, mask);
      p1 += __shfl_xor(p1, mask);
      p2 += __shfl_xor(p2, mask);
    }
    if (m16 == 0) {
      int r = (int)row0 + wave*16 + quad*4 + reg;
      float fl = out[O3 + r];
      float i0 = out[O4 + (size_t)r*3+0];
      float i1 = out[O4 + (size_t)r*3+1];
      float i2 = out[O4 + (size_t)r*3+2];
      float r0 = 0.05f * tanhf(p0 + sPar[2048]) * fl;
      float r1 = 0.05f * tanhf(p1 + sPar[2049]) * fl;
      float r2 = 0.05f * tanhf(p2 + sPar[2050]) * fl;
      out[O0 + (size_t)r*3+0] = i0 + r0;
      out[O0 + (size_t)r*3+1] = i1 + r1;
      out[O0 + (size_t)r*3+2] = i2 + r2;
      out[O2 + (size_t)r*3+0] = r0;
      out[O2 + (size_t)r*3+1] = r1;
      out[O2 + (size_t)r*3+2] = r2;
    }
  }
}

extern "C" void kernel_launch(void* const* d_in, const int* in_sizes, int n_in,
                              void* d_out, int out_size, void* d_ws, size_t ws_size,
                              hipStream_t stream) {
  (void)out_size; (void)ws_size;
  // size-based slot remap (no-op under documented dict order; protective otherwise)
  const int want[13] = {98304, 98304, 15360, 122880, 384, 384, 768, 256, 65536, 256, 768, 3, 5};
  int idx[13];
  bool used[64] = {false};
  for (int L = 0; L < 13; ++L) {
    idx[L] = -1;
    for (int s = 0; s < n_in && s < 64; ++s) {
      if (!used[s] && in_sizes[s] == want[L]) { idx[L] = s; used[s] = true; break; }
    }
    if (idx[L] < 0) idx[L] = L;
  }
  const float* pp0       = (const float*)d_in[idx[0]];
  const float* pp1       = (const float*)d_in[idx[1]];
  const float* part_pts  = (const float*)d_in[idx[2]];
  const float* part_pbw  = (const float*)d_in[idx[3]];
  const float* A         = (const float*)d_in[idx[4]];
  const float* bigA      = (const float*)d_in[idx[5]];
  const float* W1        = (const float*)d_in[idx[6]];
  const float* b1        = (const float*)d_in[idx[7]];
  const float* W2        = (const float*)d_in[idx[8]];
  const float* b2        = (const float*)d_in[idx[9]];
  const float* W3        = (const float*)d_in[idx[10]];
  const float* b3        = (const float*)d_in[idx[11]];
  const int*   lengths2  = (const int*)d_in[idx[12]];
  float* out = (float*)d_out;
  ushort_t* W2bf = (ushort_t*)d_ws;   // 128 KB of workspace

  prep_w2<<<256, 256, 0, stream>>>(W2, W2bf);
  nn_kernel<<<640, 256, 0, stream>>>(pp0, pp1, part_pts, part_pbw,
                                     A, bigA, lengths2, out);
  mlp_kernel<<<2560, 256, 0, stream>>>(W1, b1, b2, W3, b3, W2bf, out);
}

// Round 10
// 246.888 us; speedup vs baseline: 2.2460x; 1.8461x over previous
//
#include <hip/hip_runtime.h>
#include <stdint.h>
#include <math.h>

// Problem constants
#define NPTS 32768
#define PP   5
#define MM   1024
#define JJ   24
#define HH   256

// out (f32 element offsets), total 2,293,760 floats
#define O0 0                // tpose        [1,N,P,3]
#define O1 491520           // tpose_dirs   [1,N,P,3]
#define O2 983040           // resd         [1,N,P,3]
#define O3 1474560          // pflag        [1,N,P]
#define O4 1638400          // init_bigpose [1,N*P,3]
#define O5 2129920          // pnorm        [1,N*P]

typedef unsigned short ushort_t;
typedef unsigned int   uint_t;
typedef unsigned long long u64_t;
typedef __attribute__((ext_vector_type(8))) short bf16x8;
typedef __attribute__((ext_vector_type(4))) float f32x4;

__device__ __forceinline__ ushort_t f2bf(float f) {
  union { uint_t i; float f; } v; v.f = f;
  uint_t i = v.i;
  return (ushort_t)((i + 0x7FFFu + ((i >> 16) & 1u)) >> 16);  // RNE
}
__device__ __forceinline__ float tanh_fast(float v) {
  v = fminf(fmaxf(v, -15.f), 15.f);
  float e = __expf(2.f*v);               // v_exp_f32 path
  return __fdividef(e - 1.f, e + 1.f);   // abs err < 1e-6, plenty for tolerance
}

// ---------------- prep: W2 f32 -> bf16 in MFMA B-fragment order ----------------
// idx = kc*8192 + tile*512 + lane*8 + j  (lane=quad*16+(n&15), quad=(k&31)>>3, j=k&7)
__global__ __launch_bounds__(256) void prep_w2(const float* __restrict__ W2g,
                                               ushort_t* __restrict__ W2bf)
{
  int k = blockIdx.x;
  int n = threadIdx.x;
  float v = W2g[k*256 + n];
  int kc = k >> 5, quad = (k & 31) >> 3, j = k & 7;
  int tile = n >> 4, lane = quad*16 + (n & 15);
  W2bf[kc*8192 + tile*512 + lane*8 + j] = f2bf(v);
}

// ---------------- LBS transform for one (n,p) row ----------------
__device__ __forceinline__ void transform_one(
    int n, int p, int nn, float pn, float fl,
    float px, float py, float pz, float dx, float dy, float dz,
    const float* __restrict__ pbw,
    const float4* __restrict__ sA4, const float4* __restrict__ sB4,
    float* __restrict__ out)
{
  const float4* bwr = (const float4*)(pbw + ((size_t)p * MM + nn) * JJ);
  float bw[24];
  #pragma unroll
  for (int q = 0; q < 6; ++q) {
    float4 u = bwr[q];
    bw[q*4+0] = u.x; bw[q*4+1] = u.y; bw[q*4+2] = u.z; bw[q*4+3] = u.w;
  }

  float M1[12], M2[12];
  #pragma unroll
  for (int q = 0; q < 12; ++q) { M1[q] = 0.f; M2[q] = 0.f; }
  #pragma unroll
  for (int j = 0; j < 24; ++j) {
    float w = bw[j];
    float4 a0 = sA4[j*3+0], a1 = sA4[j*3+1], a2 = sA4[j*3+2];
    M1[0]=fmaf(w,a0.x,M1[0]); M1[1]=fmaf(w,a0.y,M1[1]); M1[2]=fmaf(w,a0.z,M1[2]); M1[3]=fmaf(w,a0.w,M1[3]);
    M1[4]=fmaf(w,a1.x,M1[4]); M1[5]=fmaf(w,a1.y,M1[5]); M1[6]=fmaf(w,a1.z,M1[6]); M1[7]=fmaf(w,a1.w,M1[7]);
    M1[8]=fmaf(w,a2.x,M1[8]); M1[9]=fmaf(w,a2.y,M1[9]); M1[10]=fmaf(w,a2.z,M1[10]); M1[11]=fmaf(w,a2.w,M1[11]);
    float4 c0 = sB4[j*3+0], c1 = sB4[j*3+1], c2 = sB4[j*3+2];
    M2[0]=fmaf(w,c0.x,M2[0]); M2[1]=fmaf(w,c0.y,M2[1]); M2[2]=fmaf(w,c0.z,M2[2]); M2[3]=fmaf(w,c0.w,M2[3]);
    M2[4]=fmaf(w,c1.x,M2[4]); M2[5]=fmaf(w,c1.y,M2[5]); M2[6]=fmaf(w,c1.z,M2[6]); M2[7]=fmaf(w,c1.w,M2[7]);
    M2[8]=fmaf(w,c2.x,M2[8]); M2[9]=fmaf(w,c2.y,M2[9]); M2[10]=fmaf(w,c2.z,M2[10]); M2[11]=fmaf(w,c2.w,M2[11]);
  }
  float a=M1[0], b=M1[1], c=M1[2];
  float d=M1[4], e=M1[5], f=M1[6];
  float g=M1[8], h=M1[9], i=M1[10];
  float C00 = e*i - f*h, C01 = c*h - b*i, C02 = b*f - c*e;
  float C10 = f*g - d*i, C11 = a*i - c*g, C12 = c*d - a*f;
  float C20 = d*h - e*g, C21 = b*g - a*h, C22 = a*e - b*d;
  float det = a*C00 + b*C10 + c*C20;
  float rd = 1.0f / det;
  float tx = px - M1[3], ty = py - M1[7], tz = pz - M1[11];
  float t0 = rd * (C00*tx + C01*ty + C02*tz);
  float t1 = rd * (C10*tx + C11*ty + C12*tz);
  float t2 = rd * (C20*tx + C21*ty + C22*tz);
  float i0 = M2[0]*t0 + M2[1]*t1 + M2[2]*t2  + M2[3];
  float i1 = M2[4]*t0 + M2[5]*t1 + M2[6]*t2  + M2[7];
  float i2 = M2[8]*t0 + M2[9]*t1 + M2[10]*t2 + M2[11];
  float d0 = rd * (C00*dx + C01*dy + C02*dz);
  float d1 = rd * (C10*dx + C11*dy + C12*dz);
  float d2 = rd * (C20*dx + C21*dy + C22*dz);
  float e0 = M2[0]*d0 + M2[1]*d1 + M2[2]*d2;
  float e1 = M2[4]*d0 + M2[5]*d1 + M2[6]*d2;
  float e2 = M2[8]*d0 + M2[9]*d1 + M2[10]*d2;

  size_t k = (size_t)n * PP + p;   // n-major
  out[O1 + k*3+0] = e0; out[O1 + k*3+1] = e1; out[O1 + k*3+2] = e2;
  out[O3 + k] = fl;
  out[O4 + k*3+0] = i0; out[O4 + k*3+1] = i1; out[O4 + k*3+2] = i2;
  out[O5 + k] = pn;
}

// grid: 2560 blocks x 256 threads. block b: p = b>>9, 64 n's; 4 threads per
// point scan interleaved m-slices (m ≡ s mod 4). Distance expression is
// bit-identical to the passing version; argmin via lexicographic
// (d2_bits<<32|m) min => exact first-min semantics.
__global__ __launch_bounds__(256) void nn_kernel(
    const float* __restrict__ pp0, const float* __restrict__ pp1,
    const float* __restrict__ part_pts, const float* __restrict__ pbw,
    const float* __restrict__ Ag, const float* __restrict__ Bg,
    const int* __restrict__ lengths2, float* __restrict__ out)
{
  __shared__ float4 sPart[MM];   // {x, y, z, |y|^2}
  __shared__ float4 sA4[72];
  __shared__ float4 sB4[72];
  int t = threadIdx.x;
  int p = blockIdx.x >> 9;
  int n = ((blockIdx.x & 511) << 6) + (t >> 2);
  int s = t & 3;

  // pose-pair disambiguation (wave-uniform); pose_dirs rows unit-norm
  float s0r0 = pp0[0], s0r1 = pp0[1], s0r2 = pp0[2];
  float nrm = s0r0*s0r0 + s0r1*s0r1 + s0r2*s0r2;
  bool c0_is_dirs = fabsf(nrm - 1.0f) < 1e-4f;
  const float* pose_pts  = c0_is_dirs ? pp1 : pp0;
  const float* pose_dirs = c0_is_dirs ? pp0 : pp1;

  {
    #pragma clang fp contract(off)
    for (int i = t; i < MM; i += 256) {
      float x = part_pts[((size_t)p*MM+i)*3+0];
      float y = part_pts[((size_t)p*MM+i)*3+1];
      float z = part_pts[((size_t)p*MM+i)*3+2];
      float yy = ((x*x) + (y*y)) + (z*z);
      sPart[i] = make_float4(x, y, z, yy);
    }
  }
  for (int i = t; i < 72; i += 256) {
    int l = i*4;
    int j = l / 12, rc = l % 12;
    float4 qa, qb;
    qa.x = Ag[j*16+rc+0]; qa.y = Ag[j*16+rc+1]; qa.z = Ag[j*16+rc+2]; qa.w = Ag[j*16+rc+3];
    qb.x = Bg[j*16+rc+0]; qb.y = Bg[j*16+rc+1]; qb.z = Bg[j*16+rc+2]; qb.w = Bg[j*16+rc+3];
    sA4[i] = qa; sB4[i] = qb;
  }
  int mlen = lengths2[p]; if (mlen > MM) mlen = MM;
  __syncthreads();

  float xa = pose_pts[n*3+0], ya = pose_pts[n*3+1], za = pose_pts[n*3+2];
  float dxa = pose_dirs[n*3+0], dya = pose_dirs[n*3+1], dza = pose_dirs[n*3+2];

  u64_t best = 0xFFFFFFFFFFFFFFFFull;
  {
    #pragma clang fp contract(off)
    float x2 = ((xa*xa) + (ya*ya)) + (za*za);
    int m = s;
    for (; m + 28 < mlen; m += 32) {
      float4 q[8];
      #pragma unroll
      for (int i = 0; i < 8; ++i) q[i] = sPart[m + 4*i];
      #pragma unroll
      for (int i = 0; i < 8; ++i) {
        float dt = ((xa*q[i].x) + (ya*q[i].y)) + (za*q[i].z);
        float dd = fmaxf((x2 - (2.0f*dt)) + q[i].w, 0.0f);
        u64_t pk = ((u64_t)__float_as_uint(dd) << 32) | (uint_t)(m + 4*i);
        if (pk < best) best = pk;
      }
    }
    for (; m < mlen; m += 4) {
      float4 q = sPart[m];
      float dt = ((xa*q.x) + (ya*q.y)) + (za*q.z);
      float dd = fmaxf((x2 - (2.0f*dt)) + q.w, 0.0f);
      u64_t pk = ((u64_t)__float_as_uint(dd) << 32) | (uint_t)m;
      if (pk < best) best = pk;
    }
  }
  // combine the 4 slices (lanes t^1, t^2 within the quad)
  {
    u64_t o1 = __shfl_xor(best, 1); if (o1 < best) best = o1;
    u64_t o2 = __shfl_xor(best, 2); if (o2 < best) best = o2;
  }
  if (s == 0) {
    int bm = (int)(best & 0xFFFFFFFFull);
    float bd = __uint_as_float((uint_t)(best >> 32));
    float pn = sqrtf(bd);
    float fl = ((double)pn < 0.08) ? 1.0f : 0.0f;
    transform_one(n, p, bm, pn, fl, xa, ya, za, dxa, dya, dza, pbw, sA4, sB4, out);
  }
}

// ---------------- MLP via bf16 MFMA, 32 rows/wave ----------------
// grid: 1280 blocks x 256 threads (4 waves); 128 rows/block, 32 rows/wave
// (2 M-tiles of 16). Each B-fragment load feeds 2 MFMAs.
__global__ __launch_bounds__(256) void mlp_kernel(
    const float* __restrict__ W1g, const float* __restrict__ b1g,
    const float* __restrict__ b2g, const float* __restrict__ W3g,
    const float* __restrict__ b3g, const ushort_t* __restrict__ W2bf,
    float* __restrict__ out)
{
  __shared__ float sPar[2052];  // [0,768)=W1, [768,1024)=b1, [1024,1280)=b2,
                                // [1280,2048)=W3 [k][3], [2048,2051)=b3
  int t = threadIdx.x;
  int wave = t >> 6, lane = t & 63, quad = lane >> 4, m16 = lane & 15;
  size_t row0 = (size_t)blockIdx.x * 128 + (size_t)wave * 32;

  for (int i = t; i < 2051; i += 256) {
    float v;
    if (i < 768)       v = W1g[i];
    else if (i < 1024) v = b1g[i-768];
    else if (i < 1280) v = b2g[i-1024];
    else if (i < 2048) v = W3g[i-1280];
    else               v = b3g[i-2048];
    sPar[i] = v;
  }
  __syncthreads();

  int r0 = (int)row0 + m16;        // M-tile 0 row for this lane
  int r1 = r0 + 16;                // M-tile 1 row
  float x0 = out[O4 + (size_t)r0*3+0], y0 = out[O4 + (size_t)r0*3+1], z0 = out[O4 + (size_t)r0*3+2];
  float x1 = out[O4 + (size_t)r1*3+0], y1 = out[O4 + (size_t)r1*3+1], z1 = out[O4 + (size_t)r1*3+2];

  f32x4 acc0[16], acc1[16];
  #pragma unroll
  for (int nt = 0; nt < 16; ++nt) {
    acc0[nt] = (f32x4){0.f,0.f,0.f,0.f};
    acc1[nt] = (f32x4){0.f,0.f,0.f,0.f};
  }

  for (int kc = 0; kc < 8; ++kc) {
    bf16x8 A0, A1;
    int c0 = kc*32 + quad*8;
    #pragma unroll
    for (int j = 0; j < 8; ++j) {
      int c = c0 + j;
      float w0 = sPar[c], w1 = sPar[256+c], w2 = sPar[512+c], bb = sPar[768+c];
      float h0 = fmaxf(fmaf(z0, w2, fmaf(y0, w1, fmaf(x0, w0, bb))), 0.f);
      float h1 = fmaxf(fmaf(z1, w2, fmaf(y1, w1, fmaf(x1, w0, bb))), 0.f);
      A0[j] = (short)f2bf(h0);
      A1[j] = (short)f2bf(h1);
    }
    const ushort_t* Wk = W2bf + kc*8192 + lane*8;
    #pragma unroll
    for (int nt = 0; nt < 16; ++nt) {
      bf16x8 B = *(const bf16x8*)(Wk + nt*512);
      acc0[nt] = __builtin_amdgcn_mfma_f32_16x16x32_bf16(A0, B, acc0[nt], 0, 0, 0);
      acc1[nt] = __builtin_amdgcn_mfma_f32_16x16x32_bf16(A1, B, acc1[nt], 0, 0, 0);
    }
  }

  // epilogue: h2[row=quad*4+reg][col=nt*16+m16]; layer-3 f32 + quad-reduce
  #pragma unroll
  for (int tile = 0; tile < 2; ++tile) {
    #pragma unroll
    for (int reg = 0; reg < 4; ++reg) {
      float p0 = 0.f, p1 = 0.f, p2 = 0.f;
      #pragma unroll
      for (int nt = 0; nt < 16; ++nt) {
        int col = nt*16 + m16;
        float h2v = tile ? acc1[nt][reg] : acc0[nt][reg];
        float h2 = fmaxf(h2v + sPar[1024+col], 0.f);
        p0 = fmaf(h2, sPar[1280+col*3+0], p0);
        p1 = fmaf(h2, sPar[1280+col*3+1], p1);
        p2 = fmaf(h2, sPar[1280+col*3+2], p2);
      }
      #pragma unroll
      for (int mask = 1; mask < 16; mask <<= 1) {
        p0 += __shfl_xor(p0, mask);
        p1 += __shfl_xor(p1, mask);
        p2 += __shfl_xor(p2, mask);
      }
      if (m16 == 0) {
        int r = (int)row0 + tile*16 + quad*4 + reg;
        float fl = out[O3 + r];
        float i0 = out[O4 + (size_t)r*3+0];
        float i1 = out[O4 + (size_t)r*3+1];
        float i2 = out[O4 + (size_t)r*3+2];
        float rr0 = 0.05f * tanh_fast(p0 + sPar[2048]) * fl;
        float rr1 = 0.05f * tanh_fast(p1 + sPar[2049]) * fl;
        float rr2 = 0.05f * tanh_fast(p2 + sPar[2050]) * fl;
        out[O0 + (size_t)r*3+0] = i0 + rr0;
        out[O0 + (size_t)r*3+1] = i1 + rr1;
        out[O0 + (size_t)r*3+2] = i2 + rr2;
        out[O2 + (size_t)r*3+0] = rr0;
        out[O2 + (size_t)r*3+1] = rr1;
        out[O2 + (size_t)r*3+2] = rr2;
      }
    }
  }
}

extern "C" void kernel_launch(void* const* d_in, const int* in_sizes, int n_in,
                              void* d_out, int out_size, void* d_ws, size_t ws_size,
                              hipStream_t stream) {
  (void)out_size; (void)ws_size;
  // size-based slot remap (no-op under documented dict order; protective otherwise)
  const int want[13] = {98304, 98304, 15360, 122880, 384, 384, 768, 256, 65536, 256, 768, 3, 5};
  int idx[13];
  bool used[64] = {false};
  for (int L = 0; L < 13; ++L) {
    idx[L] = -1;
    for (int s = 0; s < n_in && s < 64; ++s) {
      if (!used[s] && in_sizes[s] == want[L]) { idx[L] = s; used[s] = true; break; }
    }
    if (idx[L] < 0) idx[L] = L;
  }
  const float* pp0       = (const float*)d_in[idx[0]];
  const float* pp1       = (const float*)d_in[idx[1]];
  const float* part_pts  = (const float*)d_in[idx[2]];
  const float* part_pbw  = (const float*)d_in[idx[3]];
  const float* A         = (const float*)d_in[idx[4]];
  const float* bigA      = (const float*)d_in[idx[5]];
  const float* W1        = (const float*)d_in[idx[6]];
  const float* b1        = (const float*)d_in[idx[7]];
  const float* W2        = (const float*)d_in[idx[8]];
  const float* b2        = (const float*)d_in[idx[9]];
  const float* W3        = (const float*)d_in[idx[10]];
  const float* b3        = (const float*)d_in[idx[11]];
  const int*   lengths2  = (const int*)d_in[idx[12]];
  float* out = (float*)d_out;
  ushort_t* W2bf = (ushort_t*)d_ws;   // 128 KB of workspace

  prep_w2<<<256, 256, 0, stream>>>(W2, W2bf);
  nn_kernel<<<2560, 256, 0, stream>>>(pp0, pp1, part_pts, part_pbw,
                                      A, bigA, lengths2, out);
  mlp_kernel<<<1280, 256, 0, stream>>>(W1, b1, b2, W3, b3, W2bf, out);
}